// Round 5
// baseline (292.142 us; speedup 1.0000x reference)
//
#include <hip/hip_runtime.h>
#include <hip/hip_bf16.h>
#include <stdint.h>

// Problem constants: B=2, S=2048, D=1024, H=16, DH=64, M = B*S = 4096.

typedef __attribute__((ext_vector_type(8))) short bf16x8;
typedef __attribute__((ext_vector_type(4))) float f32x4;
typedef __attribute__((ext_vector_type(16))) float f32x16;

__device__ __forceinline__ void gld16(const void* g, void* l) {
  __builtin_amdgcn_global_load_lds((const __attribute__((address_space(1))) void*)g,
                                   (__attribute__((address_space(3))) void*)l, 16, 0, 0);
}

__device__ __forceinline__ unsigned short f2b(float f) {
  __hip_bfloat16 h = __float2bfloat16(f);
  return *reinterpret_cast<unsigned short*>(&h);
}

__device__ __forceinline__ unsigned int pk2(float a, float b) {
  return (unsigned int)f2b(a) | ((unsigned int)f2b(b) << 16);
}

// ---------------- prep: x fp32->bf16 (blocks 0..4095) + W transpose (4096..5119) ----------------
__global__ __launch_bounds__(256) void prep_kernel(const float* __restrict__ x,
                                                   const float* __restrict__ Wq,
                                                   const float* __restrict__ Wk,
                                                   const float* __restrict__ Wv,
                                                   const float* __restrict__ Wo,
                                                   unsigned short* __restrict__ xb,
                                                   unsigned short* __restrict__ wt) {
  __shared__ unsigned short Ls[64 * 72];
  int bid = blockIdx.x;
  int t = threadIdx.x;
  if (bid < 4096) {
    int i = (bid * 256 + t) * 4;
    float4 v = *(const float4*)(x + i);
    ushort4 o = make_ushort4(f2b(v.x), f2b(v.y), f2b(v.z), f2b(v.w));
    *(ushort4*)(xb + i) = o;
    return;
  }
  int tid = bid - 4096;
  int z = tid >> 8, rem = tid & 255;
  int bx = rem & 15, by = rem >> 4;
  const float* src = (z == 0) ? Wq : (z == 1) ? Wk : (z == 2) ? Wv : Wo;
  unsigned short* dst = wt + (size_t)z * 1024 * 1024;
  int k0 = bx * 64, n0 = by * 64;
  int c4 = t & 15;
#pragma unroll
  for (int it = 0; it < 4; ++it) {
    int row = it * 16 + (t >> 4);
    float4 v = *(const float4*)(src + (k0 + row) * 1024 + n0 + c4 * 4);
    Ls[(c4 * 4 + 0) * 72 + row] = f2b(v.x);
    Ls[(c4 * 4 + 1) * 72 + row] = f2b(v.y);
    Ls[(c4 * 4 + 2) * 72 + row] = f2b(v.z);
    Ls[(c4 * 4 + 3) * 72 + row] = f2b(v.w);
  }
  __syncthreads();
  int nr = t >> 2, kc = (t & 3) * 16;
  *(uint4*)(dst + (size_t)(n0 + nr) * 1024 + k0 + kc) = *(uint4*)&Ls[nr * 72 + kc];
  *(uint4*)(dst + (size_t)(n0 + nr) * 1024 + k0 + kc + 8) = *(uint4*)&Ls[nr * 72 + kc + 8];
}

// ---------------- fused QKV GEMM (unchanged from round 4) ----------------
__global__ __launch_bounds__(256) void gemm_qkv(const unsigned short* __restrict__ Ab,
                                                const unsigned short* __restrict__ Bt,
                                                const float* __restrict__ bq,
                                                const float* __restrict__ bk,
                                                const float* __restrict__ bv,
                                                unsigned short* __restrict__ qb,
                                                unsigned short* __restrict__ kb,
                                                unsigned short* __restrict__ vtb) {
  __shared__ unsigned short As[128 * 32];
  __shared__ unsigned short Bs[128 * 32];
  __shared__ unsigned short Es[128 * 72];
  const int t = threadIdx.x;
  const int lane = t & 63, wave = t >> 6;
  const int m0 = blockIdx.x * 128, n0 = blockIdx.y * 128;
  const int wr = (wave >> 1) * 64, wc = (wave & 1) * 64;
  const int fr = lane & 15, fq = lane >> 4;
  f32x4 acc[4][4] = {};
  for (int kt = 0; kt < 32; ++kt) {
    const unsigned short* Ag = Ab + (size_t)m0 * 1024 + kt * 32;
    const unsigned short* Bg = Bt + (size_t)n0 * 1024 + kt * 32;
#pragma unroll
    for (int rep = 0; rep < 2; ++rep) {
      int c = t + rep * 256;
      int row = c >> 2, col = (c & 3) * 8;
      gld16(Ag + (size_t)row * 1024 + col, (void*)(As + c * 8));
      gld16(Bg + (size_t)row * 1024 + col, (void*)(Bs + c * 8));
    }
    __syncthreads();
    bf16x8 a[4], b[4];
#pragma unroll
    for (int i = 0; i < 4; ++i) a[i] = *(const bf16x8*)&As[(wr + i * 16 + fr) * 32 + fq * 8];
#pragma unroll
    for (int j = 0; j < 4; ++j) b[j] = *(const bf16x8*)&Bs[(wc + j * 16 + fr) * 32 + fq * 8];
#pragma unroll
    for (int i = 0; i < 4; ++i)
#pragma unroll
      for (int j = 0; j < 4; ++j)
        acc[i][j] = __builtin_amdgcn_mfma_f32_16x16x32_bf16(a[i], b[j], acc[i][j], 0, 0, 0);
    __syncthreads();
  }
  const int which = n0 >> 10;
  const int bidx = m0 >> 11, s0 = m0 & 2047;
  if (which == 2) {
#pragma unroll
    for (int nh = 0; nh < 2; ++nh) {
      if ((wc >> 6) == nh) {
#pragma unroll
        for (int j = 0; j < 4; ++j) {
          int col = j * 16 + fr;
          float bias = bv[(n0 + nh * 64 + col) & 1023];
#pragma unroll
          for (int i = 0; i < 4; ++i) {
            int sl = wr + i * 16 + fq * 4;
            ushort4 pk;
            pk.x = f2b(acc[i][j][0] + bias);
            pk.y = f2b(acc[i][j][1] + bias);
            pk.z = f2b(acc[i][j][2] + bias);
            pk.w = f2b(acc[i][j][3] + bias);
            *(uint2*)&Es[col * 136 + sl] = *(uint2*)&pk;
          }
        }
      }
      __syncthreads();
      int h = ((n0 + nh * 64) & 1023) >> 6;
#pragma unroll
      for (int it = 0; it < 4; ++it) {
        int dh = it * 16 + (t >> 4);
        int ck = (t & 15) * 8;
        uint4 vv = *(uint4*)&Es[dh * 136 + ck];
        *(uint4*)&vtb[(size_t)((bidx * 16 + h) * 64 + dh) * 2048 + s0 + ck] = vv;
      }
      __syncthreads();
    }
  } else {
    unsigned short* dst = (which == 0) ? qb : kb;
    const float* bias_p = (which == 0) ? bq : bk;
    float scale = (which == 0) ? 0.1803368801111204f : 1.0f;
#pragma unroll
    for (int nh = 0; nh < 2; ++nh) {
      if ((wc >> 6) == nh) {
#pragma unroll
        for (int j = 0; j < 4; ++j) {
          int col = j * 16 + fr;
          float bias = bias_p[(n0 + nh * 64 + col) & 1023];
#pragma unroll
          for (int i = 0; i < 4; ++i)
#pragma unroll
            for (int r = 0; r < 4; ++r) {
              int sl = wr + i * 16 + fq * 4 + r;
              Es[sl * 72 + col] = f2b((acc[i][j][r] + bias) * scale);
            }
        }
      }
      __syncthreads();
      int h = ((n0 + nh * 64) & 1023) >> 6;
#pragma unroll
      for (int it = 0; it < 4; ++it) {
        int sl = it * 32 + (t >> 3);
        int ck = (t & 7) * 8;
        uint4 vv = *(uint4*)&Es[sl * 72 + ck];
        *(uint4*)&dst[(size_t)((bidx * 16 + h) * 2048 + s0 + sl) * 64 + ck] = vv;
      }
      __syncthreads();
    }
  }
}

// ---------------- flash attention v4: key-split waves, 32x32 MFMA, register P ----------------
// grid (16 q-tiles of 128, 32 bh), 256 threads. Per iter: block covers 128 keys,
// each wave a private 32-key K/V LDS tile (read exactly once). P stays in registers
// via shfl_xor(32) half-exchange. Final O/l combine through LDS (rotating chunks).
__global__ __launch_bounds__(256, 2) void attn_kernel(const unsigned short* __restrict__ qb,
                                                      const unsigned short* __restrict__ kb,
                                                      const unsigned short* __restrict__ vtb,
                                                      unsigned short* __restrict__ attn) {
  __shared__ unsigned short arena[16384];  // wave w: K at w*4096 (2048 sh), V at +2048
  __shared__ float Obuf[64 * 68];
  __shared__ float Lbuf[128];
  const int t = threadIdx.x, lane = t & 63, w = t >> 6;
  const int l31 = lane & 31, h = lane >> 5;
  const int bh = blockIdx.y, q0 = blockIdx.x * 128;
  const unsigned short* qg = qb + (size_t)bh * 2048 * 64;
  const unsigned short* kg0 = kb + (size_t)bh * 2048 * 64;
  const unsigned short* vg0 = vtb + (size_t)bh * 64 * 2048;

  // Q B-fragments, register-resident: qf[nb][s] covers q = q0+nb*32+l31, dh = s*16+h*8..+7
  bf16x8 qf[4][4];
#pragma unroll
  for (int nb = 0; nb < 4; ++nb)
#pragma unroll
    for (int s = 0; s < 4; ++s)
      qf[nb][s] = *(const bf16x8*)(qg + (size_t)(q0 + nb * 32 + l31) * 64 + s * 16 + h * 8);

  unsigned short* Kw = arena + w * 4096;
  unsigned short* Vw = Kw + 2048;
  f32x16 oacc[4][2] = {};
  float ladd[4] = {0.f, 0.f, 0.f, 0.f};

  for (int kt = 0; kt < 16; ++kt) {
    const int kbase = kt * 128 + w * 32;
    // stage K tile [32 key][64 dh], swizzled: unit(key,f) holds chunk f^(key&7)
#pragma unroll
    for (int i = 0; i < 4; ++i) {
      int key = i * 8 + (lane >> 3), f = lane & 7, d = f ^ (key & 7);
      gld16(kg0 + (size_t)(kbase + key) * 64 + d * 8, (void*)(Kw + (i * 64 + lane) * 8));
    }
    // stage V^T tile [64 dh][32 key], swizzled: unit(dh,wf) holds chunk wf^(dh&3)
#pragma unroll
    for (int i = 0; i < 4; ++i) {
      int dh = i * 16 + (lane >> 2), wf = lane & 3, ww = wf ^ (dh & 3);
      gld16(vg0 + (size_t)dh * 2048 + kbase + ww * 8, (void*)(Vw + (i * 64 + lane) * 8));
    }
    // K A-frags (m=key=l31, k=dh s*16+h*8)
    bf16x8 kf[4];
#pragma unroll
    for (int s = 0; s < 4; ++s)
      kf[s] = *(const bf16x8*)(Kw + (l31 * 8 + (((s * 2 + h) ^ (l31 & 7)))) * 8);
    // V B-frags (k=key tt*16+h*8, n=dh d2*32+l31)
    bf16x8 vf[2][2];
#pragma unroll
    for (int tt = 0; tt < 2; ++tt)
#pragma unroll
      for (int d2 = 0; d2 < 2; ++d2) {
        int dh = d2 * 32 + l31;
        vf[tt][d2] = *(const bf16x8*)(Vw + (dh * 4 + ((tt * 2 + h) ^ (dh & 3))) * 8);
      }
#pragma unroll
    for (int nb = 0; nb < 4; ++nb) {
      f32x16 sacc = {};
#pragma unroll
      for (int s = 0; s < 4; ++s)
        sacc = __builtin_amdgcn_mfma_f32_32x32x16_bf16(kf[s], qf[nb][s], sacc, 0, 0, 0);
      // exp2 (log2-domain, Q pre-scaled), pack to bf16 dwords, accumulate row-sum
      float p[16];
      float rs = 0.f;
#pragma unroll
      for (int r = 0; r < 16; ++r) {
        p[r] = __builtin_amdgcn_exp2f(sacc[r]);
        rs += p[r];
      }
      ladd[nb] += rs;
      unsigned int D[4][2];
#pragma unroll
      for (int g = 0; g < 4; ++g) {
        D[g][0] = pk2(p[4 * g + 0], p[4 * g + 1]);
        D[g][1] = pk2(p[4 * g + 2], p[4 * g + 3]);
      }
      // half-wave exchange -> PV A-frags, then PV MFMAs
#pragma unroll
      for (int tt = 0; tt < 2; ++tt) {
        unsigned int Z0 = h ? D[2 * tt][0] : D[2 * tt + 1][0];
        unsigned int Z1 = h ? D[2 * tt][1] : D[2 * tt + 1][1];
        unsigned int X0 = (unsigned int)__shfl_xor((int)Z0, 32, 64);
        unsigned int X1 = (unsigned int)__shfl_xor((int)Z1, 32, 64);
        union { unsigned int u[4]; bf16x8 v; } uu;
        uu.u[0] = h ? X0 : D[2 * tt][0];
        uu.u[1] = h ? X1 : D[2 * tt][1];
        uu.u[2] = h ? D[2 * tt + 1][0] : X0;
        uu.u[3] = h ? D[2 * tt + 1][1] : X1;
#pragma unroll
        for (int d2 = 0; d2 < 2; ++d2)
          oacc[nb][d2] = __builtin_amdgcn_mfma_f32_32x32x16_bf16(uu.v, vf[tt][d2], oacc[nb][d2], 0, 0, 0);
      }
    }
  }
  // fold key-halves of l
#pragma unroll
  for (int nb = 0; nb < 4; ++nb) ladd[nb] += __shfl_xor(ladd[nb], 32, 64);
  __syncthreads();

  const int bidx = bh >> 4, h16 = bh & 15;
#pragma unroll
  for (int p = 0; p < 2; ++p) {
    // combine: 4 rotating-chunk steps (chunk = 16 q of this pass; l chunks on pass 0)
#pragma unroll
    for (int k = 0; k < 4; ++k) {
      int c = (w + k) & 3;
      int nb = p * 2 + (c >> 1);
#pragma unroll
      for (int d2 = 0; d2 < 2; ++d2)
#pragma unroll
        for (int r2 = 0; r2 < 8; ++r2) {
          int ql = c * 16 + (r2 & 3) + 8 * (r2 >> 2) + 4 * h;
          int addr = ql * 68 + d2 * 32 + l31;
          float v = oacc[nb][d2][(c & 1) * 8 + r2];
          if (k == 0) Obuf[addr] = v; else Obuf[addr] += v;
        }
      if (p == 0 && h == 0) {
        if (k == 0) Lbuf[c * 32 + l31] = ladd[c];
        else Lbuf[c * 32 + l31] += ladd[c];
      }
      __syncthreads();
    }
    // normalize + coalesced store of this 64-q pass
    {
      int row = t >> 2, q4 = t & 3, dh0 = q4 * 16;
      float inv = 1.f / Lbuf[p * 64 + row];
      unsigned short o[16];
#pragma unroll
      for (int i = 0; i < 16; ++i) o[i] = f2b(Obuf[row * 68 + dh0 + i] * inv);
      size_t base = (size_t)(bidx * 2048 + q0 + p * 64 + row) * 1024 + h16 * 64 + dh0;
      *(uint4*)&attn[base] = *(uint4*)&o[0];
      *(uint4*)&attn[base + 8] = *(uint4*)&o[8];
    }
    __syncthreads();
  }
}

// ---------------- output projection (unchanged) ----------------
__global__ __launch_bounds__(256) void gemm_out(const unsigned short* __restrict__ Ab,
                                                const unsigned short* __restrict__ Bt,
                                                const float* __restrict__ bo,
                                                float* __restrict__ out) {
  __shared__ unsigned short As[128 * 32];
  __shared__ unsigned short Bs[128 * 32];
  const int t = threadIdx.x;
  const int lane = t & 63, wave = t >> 6;
  const int m0 = blockIdx.x * 128, n0 = blockIdx.y * 128;
  const int wr = (wave >> 1) * 64, wc = (wave & 1) * 64;
  const int fr = lane & 15, fq = lane >> 4;
  f32x4 acc[4][4] = {};
  for (int kt = 0; kt < 32; ++kt) {
    const unsigned short* Ag = Ab + (size_t)m0 * 1024 + kt * 32;
    const unsigned short* Bg = Bt + (size_t)n0 * 1024 + kt * 32;
#pragma unroll
    for (int rep = 0; rep < 2; ++rep) {
      int c = t + rep * 256;
      int row = c >> 2, col = (c & 3) * 8;
      gld16(Ag + (size_t)row * 1024 + col, (void*)(As + c * 8));
      gld16(Bg + (size_t)row * 1024 + col, (void*)(Bs + c * 8));
    }
    __syncthreads();
    bf16x8 a[4], b[4];
#pragma unroll
    for (int i = 0; i < 4; ++i) a[i] = *(const bf16x8*)&As[(wr + i * 16 + fr) * 32 + fq * 8];
#pragma unroll
    for (int j = 0; j < 4; ++j) b[j] = *(const bf16x8*)&Bs[(wc + j * 16 + fr) * 32 + fq * 8];
#pragma unroll
    for (int i = 0; i < 4; ++i)
#pragma unroll
      for (int j = 0; j < 4; ++j)
        acc[i][j] = __builtin_amdgcn_mfma_f32_16x16x32_bf16(a[i], b[j], acc[i][j], 0, 0, 0);
    __syncthreads();
  }
#pragma unroll
  for (int j = 0; j < 4; ++j) {
    int gn = n0 + wc + j * 16 + fr;
    float bias = bo[gn];
#pragma unroll
    for (int i = 0; i < 4; ++i)
#pragma unroll
      for (int r = 0; r < 4; ++r) {
        int gm = m0 + wr + i * 16 + fq * 4 + r;
        out[(size_t)gm * 1024 + gn] = acc[i][j][r] + bias;
      }
  }
}

extern "C" void kernel_launch(void* const* d_in, const int* in_sizes, int n_in,
                              void* d_out, int out_size, void* d_ws, size_t ws_size,
                              hipStream_t stream) {
  const float* x = (const float*)d_in[0];
  const float* Wq = (const float*)d_in[1];
  const float* bq = (const float*)d_in[2];
  const float* Wk = (const float*)d_in[3];
  const float* bk = (const float*)d_in[4];
  const float* Wv = (const float*)d_in[5];
  const float* bv = (const float*)d_in[6];
  const float* Wo = (const float*)d_in[7];
  const float* bo = (const float*)d_in[8];
  float* out = (float*)d_out;

  unsigned short* ws = (unsigned short*)d_ws;
  const size_t MI = (size_t)1024 * 1024;
  unsigned short* xb = ws;
  unsigned short* wt = ws + 4 * MI;
  unsigned short* qb = wt + 4 * MI;
  unsigned short* kb = qb + 4 * MI;
  unsigned short* vtb = kb + 4 * MI;
  unsigned short* attn = xb;  // reuse xb after QKV gemm

  prep_kernel<<<5120, 256, 0, stream>>>(x, Wq, Wk, Wv, Wo, xb, wt);
  gemm_qkv<<<dim3(32, 24), 256, 0, stream>>>(xb, wt, bq, bk, bv, qb, kb, vtb);
  attn_kernel<<<dim3(16, 32), 256, 0, stream>>>(qb, kb, vtb, attn);
  gemm_out<<<dim3(32, 8), 256, 0, stream>>>(attn, wt + 3 * MI, bo, out);
}

// Round 7
// 258.208 us; speedup vs baseline: 1.1314x; 1.1314x over previous
//
#include <hip/hip_runtime.h>
#include <hip/hip_bf16.h>
#include <stdint.h>

// Problem constants: B=2, S=2048, D=1024, H=16, DH=64, M = B*S = 4096.

typedef __attribute__((ext_vector_type(8))) short bf16x8;
typedef __attribute__((ext_vector_type(4))) float f32x4;
typedef __attribute__((ext_vector_type(16))) float f32x16;

__device__ __forceinline__ void gld16(const void* g, void* l) {
  __builtin_amdgcn_global_load_lds((const __attribute__((address_space(1))) void*)g,
                                   (__attribute__((address_space(3))) void*)l, 16, 0, 0);
}

__device__ __forceinline__ unsigned short f2b(float f) {
  __hip_bfloat16 h = __float2bfloat16(f);
  return *reinterpret_cast<unsigned short*>(&h);
}

__device__ __forceinline__ unsigned int pk2(float a, float b) {
  return (unsigned int)f2b(a) | ((unsigned int)f2b(b) << 16);
}

// ---------------- prep: x fp32->bf16 (blocks 0..4095) + W transpose (4096..5119) ----------------
__global__ __launch_bounds__(256) void prep_kernel(const float* __restrict__ x,
                                                   const float* __restrict__ Wq,
                                                   const float* __restrict__ Wk,
                                                   const float* __restrict__ Wv,
                                                   const float* __restrict__ Wo,
                                                   unsigned short* __restrict__ xb,
                                                   unsigned short* __restrict__ wt) {
  __shared__ unsigned short Ls[64 * 72];
  int bid = blockIdx.x;
  int t = threadIdx.x;
  if (bid < 4096) {
    int i = (bid * 256 + t) * 4;
    float4 v = *(const float4*)(x + i);
    ushort4 o = make_ushort4(f2b(v.x), f2b(v.y), f2b(v.z), f2b(v.w));
    *(ushort4*)(xb + i) = o;
    return;
  }
  int tid = bid - 4096;
  int z = tid >> 8, rem = tid & 255;
  int bx = rem & 15, by = rem >> 4;
  const float* src = (z == 0) ? Wq : (z == 1) ? Wk : (z == 2) ? Wv : Wo;
  unsigned short* dst = wt + (size_t)z * 1024 * 1024;
  int k0 = bx * 64, n0 = by * 64;
  int c4 = t & 15;
#pragma unroll
  for (int it = 0; it < 4; ++it) {
    int row = it * 16 + (t >> 4);
    float4 v = *(const float4*)(src + (k0 + row) * 1024 + n0 + c4 * 4);
    Ls[(c4 * 4 + 0) * 72 + row] = f2b(v.x);
    Ls[(c4 * 4 + 1) * 72 + row] = f2b(v.y);
    Ls[(c4 * 4 + 2) * 72 + row] = f2b(v.z);
    Ls[(c4 * 4 + 3) * 72 + row] = f2b(v.w);
  }
  __syncthreads();
  int nr = t >> 2, kc = (t & 3) * 16;
  *(uint4*)(dst + (size_t)(n0 + nr) * 1024 + k0 + kc) = *(uint4*)&Ls[nr * 72 + kc];
  *(uint4*)(dst + (size_t)(n0 + nr) * 1024 + k0 + kc + 8) = *(uint4*)&Ls[nr * 72 + kc + 8];
}

// ---------------- fused QKV GEMM (unchanged) ----------------
__global__ __launch_bounds__(256) void gemm_qkv(const unsigned short* __restrict__ Ab,
                                                const unsigned short* __restrict__ Bt,
                                                const float* __restrict__ bq,
                                                const float* __restrict__ bk,
                                                const float* __restrict__ bv,
                                                unsigned short* __restrict__ qb,
                                                unsigned short* __restrict__ kb,
                                                unsigned short* __restrict__ vtb) {
  __shared__ unsigned short As[128 * 32];
  __shared__ unsigned short Bs[128 * 32];
  __shared__ unsigned short Es[128 * 72];
  const int t = threadIdx.x;
  const int lane = t & 63, wave = t >> 6;
  const int m0 = blockIdx.x * 128, n0 = blockIdx.y * 128;
  const int wr = (wave >> 1) * 64, wc = (wave & 1) * 64;
  const int fr = lane & 15, fq = lane >> 4;
  f32x4 acc[4][4] = {};
  for (int kt = 0; kt < 32; ++kt) {
    const unsigned short* Ag = Ab + (size_t)m0 * 1024 + kt * 32;
    const unsigned short* Bg = Bt + (size_t)n0 * 1024 + kt * 32;
#pragma unroll
    for (int rep = 0; rep < 2; ++rep) {
      int c = t + rep * 256;
      int row = c >> 2, col = (c & 3) * 8;
      gld16(Ag + (size_t)row * 1024 + col, (void*)(As + c * 8));
      gld16(Bg + (size_t)row * 1024 + col, (void*)(Bs + c * 8));
    }
    __syncthreads();
    bf16x8 a[4], b[4];
#pragma unroll
    for (int i = 0; i < 4; ++i) a[i] = *(const bf16x8*)&As[(wr + i * 16 + fr) * 32 + fq * 8];
#pragma unroll
    for (int j = 0; j < 4; ++j) b[j] = *(const bf16x8*)&Bs[(wc + j * 16 + fr) * 32 + fq * 8];
#pragma unroll
    for (int i = 0; i < 4; ++i)
#pragma unroll
      for (int j = 0; j < 4; ++j)
        acc[i][j] = __builtin_amdgcn_mfma_f32_16x16x32_bf16(a[i], b[j], acc[i][j], 0, 0, 0);
    __syncthreads();
  }
  const int which = n0 >> 10;
  const int bidx = m0 >> 11, s0 = m0 & 2047;
  if (which == 2) {
#pragma unroll
    for (int nh = 0; nh < 2; ++nh) {
      if ((wc >> 6) == nh) {
#pragma unroll
        for (int j = 0; j < 4; ++j) {
          int col = j * 16 + fr;
          float bias = bv[(n0 + nh * 64 + col) & 1023];
#pragma unroll
          for (int i = 0; i < 4; ++i) {
            int sl = wr + i * 16 + fq * 4;
            ushort4 pk;
            pk.x = f2b(acc[i][j][0] + bias);
            pk.y = f2b(acc[i][j][1] + bias);
            pk.z = f2b(acc[i][j][2] + bias);
            pk.w = f2b(acc[i][j][3] + bias);
            *(uint2*)&Es[col * 136 + sl] = *(uint2*)&pk;
          }
        }
      }
      __syncthreads();
      int h = ((n0 + nh * 64) & 1023) >> 6;
#pragma unroll
      for (int it = 0; it < 4; ++it) {
        int dh = it * 16 + (t >> 4);
        int ck = (t & 15) * 8;
        uint4 vv = *(uint4*)&Es[dh * 136 + ck];
        *(uint4*)&vtb[(size_t)((bidx * 16 + h) * 64 + dh) * 2048 + s0 + ck] = vv;
      }
      __syncthreads();
    }
  } else {
    unsigned short* dst = (which == 0) ? qb : kb;
    const float* bias_p = (which == 0) ? bq : bk;
    float scale = (which == 0) ? 0.1803368801111204f : 1.0f;
#pragma unroll
    for (int nh = 0; nh < 2; ++nh) {
      if ((wc >> 6) == nh) {
#pragma unroll
        for (int j = 0; j < 4; ++j) {
          int col = j * 16 + fr;
          float bias = bias_p[(n0 + nh * 64 + col) & 1023];
#pragma unroll
          for (int i = 0; i < 4; ++i)
#pragma unroll
            for (int r = 0; r < 4; ++r) {
              int sl = wr + i * 16 + fq * 4 + r;
              Es[sl * 72 + col] = f2b((acc[i][j][r] + bias) * scale);
            }
        }
      }
      __syncthreads();
      int h = ((n0 + nh * 64) & 1023) >> 6;
#pragma unroll
      for (int it = 0; it < 4; ++it) {
        int sl = it * 32 + (t >> 3);
        int ck = (t & 7) * 8;
        uint4 vv = *(uint4*)&Es[sl * 72 + ck];
        *(uint4*)&dst[(size_t)((bidx * 16 + h) * 2048 + s0 + sl) * 64 + ck] = vv;
      }
      __syncthreads();
    }
  }
}

// ---------------- flash attention v6: v5 + explicit vmcnt/lgkmcnt wait discipline ----------------
// grid (32 q-tiles of 64, 32 bh), 256 threads. Block covers 128 keys/iter; each wave a
// private 32-key K/V LDS tile (read exactly once). P never touches LDS.
// Pipeline per iter: wait vmcnt(0) -> ds_read frags -> wait lgkmcnt(0) -> stage kt+1 -> compute.
__global__ __launch_bounds__(256, 2) void attn_kernel(const unsigned short* __restrict__ qb,
                                                      const unsigned short* __restrict__ kb,
                                                      const unsigned short* __restrict__ vtb,
                                                      unsigned short* __restrict__ attn) {
  __shared__ unsigned short arena[16384];  // wave w: K at w*4096 (2048 sh), V at +2048
  __shared__ float Obuf[64 * 68];
  __shared__ float Lbuf[64];
  const int t = threadIdx.x, lane = t & 63, w = t >> 6;
  const int l31 = lane & 31, h = lane >> 5;
  const int bh = blockIdx.y, q0 = blockIdx.x * 64;
  const unsigned short* qg = qb + (size_t)bh * 2048 * 64;
  const unsigned short* kg0 = kb + (size_t)bh * 2048 * 64;
  const unsigned short* vg0 = vtb + (size_t)bh * 64 * 2048;

  // Q B-fragments, register-resident: qf[nb][s] covers q = q0+nb*32+l31, dh = s*16+h*8..+7
  bf16x8 qf[2][4];
#pragma unroll
  for (int nb = 0; nb < 2; ++nb)
#pragma unroll
    for (int s = 0; s < 4; ++s)
      qf[nb][s] = *(const bf16x8*)(qg + (size_t)(q0 + nb * 32 + l31) * 64 + s * 16 + h * 8);

  unsigned short* Kw = arena + w * 4096;
  unsigned short* Vw = Kw + 2048;
  f32x16 oacc[2][2] = {};
  float ladd[2] = {0.f, 0.f};

  // stage tile 0
  {
    const int kbase = w * 32;
#pragma unroll
    for (int i = 0; i < 4; ++i) {
      int key = i * 8 + (lane >> 3), f = lane & 7, d = f ^ (key & 7);
      gld16(kg0 + (size_t)(kbase + key) * 64 + d * 8, (void*)(Kw + (i * 64 + lane) * 8));
    }
#pragma unroll
    for (int i = 0; i < 4; ++i) {
      int dh = i * 16 + (lane >> 2), wf = lane & 3, ww = wf ^ (dh & 3);
      gld16(vg0 + (size_t)dh * 2048 + kbase + ww * 8, (void*)(Vw + (i * 64 + lane) * 8));
    }
  }

  for (int kt = 0; kt < 16; ++kt) {
    // tile kt resident only after all outstanding global->LDS DMAs retire
    __builtin_amdgcn_s_waitcnt(0x0f70);  // vmcnt(0)
    // K A-frags (m=key=l31, k=dh s*16+h*8)
    bf16x8 kf[4];
#pragma unroll
    for (int s = 0; s < 4; ++s)
      kf[s] = *(const bf16x8*)(Kw + (l31 * 8 + (((s * 2 + h) ^ (l31 & 7)))) * 8);
    // V B-frags (k=key tt*16+h*8, n=dh d2*32+l31)
    bf16x8 vf[2][2];
#pragma unroll
    for (int tt = 0; tt < 2; ++tt)
#pragma unroll
      for (int d2 = 0; d2 < 2; ++d2) {
        int dh = d2 * 32 + l31;
        vf[tt][d2] = *(const bf16x8*)(Vw + (dh * 4 + ((tt * 2 + h) ^ (dh & 3))) * 8);
      }
    // frags now requested; drain LDS reads before overwriting the tile
    __builtin_amdgcn_s_waitcnt(0xc07f);  // lgkmcnt(0)
    if (kt + 1 < 16) {
      const int kbase = (kt + 1) * 128 + w * 32;
#pragma unroll
      for (int i = 0; i < 4; ++i) {
        int key = i * 8 + (lane >> 3), f = lane & 7, d = f ^ (key & 7);
        gld16(kg0 + (size_t)(kbase + key) * 64 + d * 8, (void*)(Kw + (i * 64 + lane) * 8));
      }
#pragma unroll
      for (int i = 0; i < 4; ++i) {
        int dh = i * 16 + (lane >> 2), wf = lane & 3, ww = wf ^ (dh & 3);
        gld16(vg0 + (size_t)dh * 2048 + kbase + ww * 8, (void*)(Vw + (i * 64 + lane) * 8));
      }
    }
#pragma unroll
    for (int nb = 0; nb < 2; ++nb) {
      f32x16 sacc = {};
#pragma unroll
      for (int s = 0; s < 4; ++s)
        sacc = __builtin_amdgcn_mfma_f32_32x32x16_bf16(kf[s], qf[nb][s], sacc, 0, 0, 0);
      // exp2 (log2-domain, Q pre-scaled), pack to bf16 dwords, accumulate row-sum
      float p[16];
      float rs = 0.f;
#pragma unroll
      for (int r = 0; r < 16; ++r) {
        p[r] = __builtin_amdgcn_exp2f(sacc[r]);
        rs += p[r];
      }
      ladd[nb] += rs;
      unsigned int D[4][2];
#pragma unroll
      for (int g = 0; g < 4; ++g) {
        D[g][0] = pk2(p[4 * g + 0], p[4 * g + 1]);
        D[g][1] = pk2(p[4 * g + 2], p[4 * g + 3]);
      }
      // half-wave exchange -> PV A-frags, then PV MFMAs
#pragma unroll
      for (int tt = 0; tt < 2; ++tt) {
        unsigned int Z0 = h ? D[2 * tt][0] : D[2 * tt + 1][0];
        unsigned int Z1 = h ? D[2 * tt][1] : D[2 * tt + 1][1];
        unsigned int X0 = (unsigned int)__shfl_xor((int)Z0, 32, 64);
        unsigned int X1 = (unsigned int)__shfl_xor((int)Z1, 32, 64);
        union { unsigned int u[4]; bf16x8 v; } uu;
        uu.u[0] = h ? X0 : D[2 * tt][0];
        uu.u[1] = h ? X1 : D[2 * tt][1];
        uu.u[2] = h ? D[2 * tt + 1][0] : X0;
        uu.u[3] = h ? D[2 * tt + 1][1] : X1;
#pragma unroll
        for (int d2 = 0; d2 < 2; ++d2)
          oacc[nb][d2] = __builtin_amdgcn_mfma_f32_32x32x16_bf16(uu.v, vf[tt][d2], oacc[nb][d2], 0, 0, 0);
      }
    }
  }
  // fold key-halves of l
#pragma unroll
  for (int nb = 0; nb < 2; ++nb) ladd[nb] += __shfl_xor(ladd[nb], 32, 64);
  __syncthreads();

  const int bidx = bh >> 4, h16 = bh & 15;
  // combine: 4 rotating-chunk steps (chunk = 16 q rows)
#pragma unroll
  for (int k = 0; k < 4; ++k) {
    int c = (w + k) & 3;
    int nb = c >> 1;
#pragma unroll
    for (int d2 = 0; d2 < 2; ++d2)
#pragma unroll
      for (int r2 = 0; r2 < 8; ++r2) {
        int ql = c * 16 + (r2 & 3) + 8 * (r2 >> 2) + 4 * h;
        int addr = ql * 68 + d2 * 32 + l31;
        float v = oacc[nb][d2][(c & 1) * 8 + r2];
        if (k == 0) Obuf[addr] = v; else Obuf[addr] += v;
      }
    if (h == 0 && (l31 >> 4) == (c & 1)) {
      int qi = c * 16 + (l31 & 15);
      if (k == 0) Lbuf[qi] = ladd[nb]; else Lbuf[qi] += ladd[nb];
    }
    __syncthreads();
  }
  // normalize + coalesced store
  {
    int row = t >> 2, dh0 = (t & 3) * 16;
    float inv = 1.f / Lbuf[row];
    unsigned short o[16];
#pragma unroll
    for (int i = 0; i < 16; ++i) o[i] = f2b(Obuf[row * 68 + dh0 + i] * inv);
    size_t base = (size_t)(bidx * 2048 + q0 + row) * 1024 + h16 * 64 + dh0;
    *(uint4*)&attn[base] = *(uint4*)&o[0];
    *(uint4*)&attn[base + 8] = *(uint4*)&o[8];
  }
}

// ---------------- output projection (unchanged) ----------------
__global__ __launch_bounds__(256) void gemm_out(const unsigned short* __restrict__ Ab,
                                                const unsigned short* __restrict__ Bt,
                                                const float* __restrict__ bo,
                                                float* __restrict__ out) {
  __shared__ unsigned short As[128 * 32];
  __shared__ unsigned short Bs[128 * 32];
  const int t = threadIdx.x;
  const int lane = t & 63, wave = t >> 6;
  const int m0 = blockIdx.x * 128, n0 = blockIdx.y * 128;
  const int wr = (wave >> 1) * 64, wc = (wave & 1) * 64;
  const int fr = lane & 15, fq = lane >> 4;
  f32x4 acc[4][4] = {};
  for (int kt = 0; kt < 32; ++kt) {
    const unsigned short* Ag = Ab + (size_t)m0 * 1024 + kt * 32;
    const unsigned short* Bg = Bt + (size_t)n0 * 1024 + kt * 32;
#pragma unroll
    for (int rep = 0; rep < 2; ++rep) {
      int c = t + rep * 256;
      int row = c >> 2, col = (c & 3) * 8;
      gld16(Ag + (size_t)row * 1024 + col, (void*)(As + c * 8));
      gld16(Bg + (size_t)row * 1024 + col, (void*)(Bs + c * 8));
    }
    __syncthreads();
    bf16x8 a[4], b[4];
#pragma unroll
    for (int i = 0; i < 4; ++i) a[i] = *(const bf16x8*)&As[(wr + i * 16 + fr) * 32 + fq * 8];
#pragma unroll
    for (int j = 0; j < 4; ++j) b[j] = *(const bf16x8*)&Bs[(wc + j * 16 + fr) * 32 + fq * 8];
#pragma unroll
    for (int i = 0; i < 4; ++i)
#pragma unroll
      for (int j = 0; j < 4; ++j)
        acc[i][j] = __builtin_amdgcn_mfma_f32_16x16x32_bf16(a[i], b[j], acc[i][j], 0, 0, 0);
    __syncthreads();
  }
#pragma unroll
  for (int j = 0; j < 4; ++j) {
    int gn = n0 + wc + j * 16 + fr;
    float bias = bo[gn];
#pragma unroll
    for (int i = 0; i < 4; ++i)
#pragma unroll
      for (int r = 0; r < 4; ++r) {
        int gm = m0 + wr + i * 16 + fq * 4 + r;
        out[(size_t)gm * 1024 + gn] = acc[i][j][r] + bias;
      }
  }
}

extern "C" void kernel_launch(void* const* d_in, const int* in_sizes, int n_in,
                              void* d_out, int out_size, void* d_ws, size_t ws_size,
                              hipStream_t stream) {
  const float* x = (const float*)d_in[0];
  const float* Wq = (const float*)d_in[1];
  const float* bq = (const float*)d_in[2];
  const float* Wk = (const float*)d_in[3];
  const float* bk = (const float*)d_in[4];
  const float* Wv = (const float*)d_in[5];
  const float* bv = (const float*)d_in[6];
  const float* Wo = (const float*)d_in[7];
  const float* bo = (const float*)d_in[8];
  float* out = (float*)d_out;

  unsigned short* ws = (unsigned short*)d_ws;
  const size_t MI = (size_t)1024 * 1024;
  unsigned short* xb = ws;
  unsigned short* wt = ws + 4 * MI;
  unsigned short* qb = wt + 4 * MI;
  unsigned short* kb = qb + 4 * MI;
  unsigned short* vtb = kb + 4 * MI;
  unsigned short* attn = xb;  // reuse xb after QKV gemm

  prep_kernel<<<5120, 256, 0, stream>>>(x, Wq, Wk, Wv, Wo, xb, wt);
  gemm_qkv<<<dim3(32, 24), 256, 0, stream>>>(xb, wt, bq, bk, bv, qb, kb, vtb);
  attn_kernel<<<dim3(32, 32), 256, 0, stream>>>(qb, kb, vtb, attn);
  gemm_out<<<dim3(32, 8), 256, 0, stream>>>(attn, wt + 3 * MI, bo, out);
}

// Round 8
// 253.637 us; speedup vs baseline: 1.1518x; 1.0180x over previous
//
#include <hip/hip_runtime.h>
#include <hip/hip_bf16.h>
#include <stdint.h>

// Problem constants: B=2, S=2048, D=1024, H=16, DH=64, M = B*S = 4096.

typedef __attribute__((ext_vector_type(8))) short bf16x8;
typedef __attribute__((ext_vector_type(4))) float f32x4;
typedef __attribute__((ext_vector_type(16))) float f32x16;

__device__ __forceinline__ void gld16(const void* g, void* l) {
  __builtin_amdgcn_global_load_lds((const __attribute__((address_space(1))) void*)g,
                                   (__attribute__((address_space(3))) void*)l, 16, 0, 0);
}

__device__ __forceinline__ unsigned short f2b(float f) {
  __hip_bfloat16 h = __float2bfloat16(f);
  return *reinterpret_cast<unsigned short*>(&h);
}

__device__ __forceinline__ unsigned int pk2(float a, float b) {
  return (unsigned int)f2b(a) | ((unsigned int)f2b(b) << 16);
}

// ---------------- prep: x fp32->bf16 (blocks 0..4095) + W transpose (4096..5119) ----------------
__global__ __launch_bounds__(256) void prep_kernel(const float* __restrict__ x,
                                                   const float* __restrict__ Wq,
                                                   const float* __restrict__ Wk,
                                                   const float* __restrict__ Wv,
                                                   const float* __restrict__ Wo,
                                                   unsigned short* __restrict__ xb,
                                                   unsigned short* __restrict__ wt) {
  __shared__ unsigned short Ls[64 * 72];
  int bid = blockIdx.x;
  int t = threadIdx.x;
  if (bid < 4096) {
    int i = (bid * 256 + t) * 4;
    float4 v = *(const float4*)(x + i);
    ushort4 o = make_ushort4(f2b(v.x), f2b(v.y), f2b(v.z), f2b(v.w));
    *(ushort4*)(xb + i) = o;
    return;
  }
  int tid = bid - 4096;
  int z = tid >> 8, rem = tid & 255;
  int bx = rem & 15, by = rem >> 4;
  const float* src = (z == 0) ? Wq : (z == 1) ? Wk : (z == 2) ? Wv : Wo;
  unsigned short* dst = wt + (size_t)z * 1024 * 1024;
  int k0 = bx * 64, n0 = by * 64;
  int c4 = t & 15;
#pragma unroll
  for (int it = 0; it < 4; ++it) {
    int row = it * 16 + (t >> 4);
    float4 v = *(const float4*)(src + (k0 + row) * 1024 + n0 + c4 * 4);
    Ls[(c4 * 4 + 0) * 72 + row] = f2b(v.x);
    Ls[(c4 * 4 + 1) * 72 + row] = f2b(v.y);
    Ls[(c4 * 4 + 2) * 72 + row] = f2b(v.z);
    Ls[(c4 * 4 + 3) * 72 + row] = f2b(v.w);
  }
  __syncthreads();
  int nr = t >> 2, kc = (t & 3) * 16;
  *(uint4*)(dst + (size_t)(n0 + nr) * 1024 + k0 + kc) = *(uint4*)&Ls[nr * 72 + kc];
  *(uint4*)(dst + (size_t)(n0 + nr) * 1024 + k0 + kc + 8) = *(uint4*)&Ls[nr * 72 + kc + 8];
}

// ---------------- fused QKV GEMM (unchanged) ----------------
__global__ __launch_bounds__(256) void gemm_qkv(const unsigned short* __restrict__ Ab,
                                                const unsigned short* __restrict__ Bt,
                                                const float* __restrict__ bq,
                                                const float* __restrict__ bk,
                                                const float* __restrict__ bv,
                                                unsigned short* __restrict__ qb,
                                                unsigned short* __restrict__ kb,
                                                unsigned short* __restrict__ vtb) {
  __shared__ unsigned short As[128 * 32];
  __shared__ unsigned short Bs[128 * 32];
  __shared__ unsigned short Es[128 * 72];
  const int t = threadIdx.x;
  const int lane = t & 63, wave = t >> 6;
  const int m0 = blockIdx.x * 128, n0 = blockIdx.y * 128;
  const int wr = (wave >> 1) * 64, wc = (wave & 1) * 64;
  const int fr = lane & 15, fq = lane >> 4;
  f32x4 acc[4][4] = {};
  for (int kt = 0; kt < 32; ++kt) {
    const unsigned short* Ag = Ab + (size_t)m0 * 1024 + kt * 32;
    const unsigned short* Bg = Bt + (size_t)n0 * 1024 + kt * 32;
#pragma unroll
    for (int rep = 0; rep < 2; ++rep) {
      int c = t + rep * 256;
      int row = c >> 2, col = (c & 3) * 8;
      gld16(Ag + (size_t)row * 1024 + col, (void*)(As + c * 8));
      gld16(Bg + (size_t)row * 1024 + col, (void*)(Bs + c * 8));
    }
    __syncthreads();
    bf16x8 a[4], b[4];
#pragma unroll
    for (int i = 0; i < 4; ++i) a[i] = *(const bf16x8*)&As[(wr + i * 16 + fr) * 32 + fq * 8];
#pragma unroll
    for (int j = 0; j < 4; ++j) b[j] = *(const bf16x8*)&Bs[(wc + j * 16 + fr) * 32 + fq * 8];
#pragma unroll
    for (int i = 0; i < 4; ++i)
#pragma unroll
      for (int j = 0; j < 4; ++j)
        acc[i][j] = __builtin_amdgcn_mfma_f32_16x16x32_bf16(a[i], b[j], acc[i][j], 0, 0, 0);
    __syncthreads();
  }
  const int which = n0 >> 10;
  const int bidx = m0 >> 11, s0 = m0 & 2047;
  if (which == 2) {
#pragma unroll
    for (int nh = 0; nh < 2; ++nh) {
      if ((wc >> 6) == nh) {
#pragma unroll
        for (int j = 0; j < 4; ++j) {
          int col = j * 16 + fr;
          float bias = bv[(n0 + nh * 64 + col) & 1023];
#pragma unroll
          for (int i = 0; i < 4; ++i) {
            int sl = wr + i * 16 + fq * 4;
            ushort4 pk;
            pk.x = f2b(acc[i][j][0] + bias);
            pk.y = f2b(acc[i][j][1] + bias);
            pk.z = f2b(acc[i][j][2] + bias);
            pk.w = f2b(acc[i][j][3] + bias);
            *(uint2*)&Es[col * 136 + sl] = *(uint2*)&pk;
          }
        }
      }
      __syncthreads();
      int h = ((n0 + nh * 64) & 1023) >> 6;
#pragma unroll
      for (int it = 0; it < 4; ++it) {
        int dh = it * 16 + (t >> 4);
        int ck = (t & 15) * 8;
        uint4 vv = *(uint4*)&Es[dh * 136 + ck];
        *(uint4*)&vtb[(size_t)((bidx * 16 + h) * 64 + dh) * 2048 + s0 + ck] = vv;
      }
      __syncthreads();
    }
  } else {
    unsigned short* dst = (which == 0) ? qb : kb;
    const float* bias_p = (which == 0) ? bq : bk;
    float scale = (which == 0) ? 0.1803368801111204f : 1.0f;
#pragma unroll
    for (int nh = 0; nh < 2; ++nh) {
      if ((wc >> 6) == nh) {
#pragma unroll
        for (int j = 0; j < 4; ++j) {
          int col = j * 16 + fr;
          float bias = bias_p[(n0 + nh * 64 + col) & 1023];
#pragma unroll
          for (int i = 0; i < 4; ++i)
#pragma unroll
            for (int r = 0; r < 4; ++r) {
              int sl = wr + i * 16 + fq * 4 + r;
              Es[sl * 72 + col] = f2b((acc[i][j][r] + bias) * scale);
            }
        }
      }
      __syncthreads();
      int h = ((n0 + nh * 64) & 1023) >> 6;
#pragma unroll
      for (int it = 0; it < 4; ++it) {
        int sl = it * 32 + (t >> 3);
        int ck = (t & 7) * 8;
        uint4 vv = *(uint4*)&Es[sl * 72 + ck];
        *(uint4*)&dst[(size_t)((bidx * 16 + h) * 2048 + s0 + sl) * 64 + ck] = vv;
      }
      __syncthreads();
    }
  }
}

// ---------------- flash attention v7: v6 + free register budget + bh->XCD pinning ----------------
// grid (32 bh, 32 q-tiles), 256 threads: workgroup id = qt*32+bh -> XCD = bh%8, so each
// bh's K/V (512 KB) stays in one XCD's L2. Block covers 128 keys/iter; each wave a private
// 32-key K/V LDS tile (read exactly once). P never touches LDS.
// Pipeline per iter: wait vmcnt(0) -> ds_read frags -> wait lgkmcnt(0) -> stage kt+1 -> compute.
__global__ __launch_bounds__(256) void attn_kernel(const unsigned short* __restrict__ qb,
                                                   const unsigned short* __restrict__ kb,
                                                   const unsigned short* __restrict__ vtb,
                                                   unsigned short* __restrict__ attn) {
  __shared__ unsigned short arena[16384];  // wave w: K at w*4096 (2048 sh), V at +2048
  __shared__ float Obuf[64 * 68];
  __shared__ float Lbuf[64];
  const int t = threadIdx.x, lane = t & 63, w = t >> 6;
  const int l31 = lane & 31, h = lane >> 5;
  const int bh = blockIdx.x, q0 = blockIdx.y * 64;
  const unsigned short* qg = qb + (size_t)bh * 2048 * 64;
  const unsigned short* kg0 = kb + (size_t)bh * 2048 * 64;
  const unsigned short* vg0 = vtb + (size_t)bh * 64 * 2048;

  // Q B-fragments, register-resident: qf[nb][s] covers q = q0+nb*32+l31, dh = s*16+h*8..+7
  bf16x8 qf[2][4];
#pragma unroll
  for (int nb = 0; nb < 2; ++nb)
#pragma unroll
    for (int s = 0; s < 4; ++s)
      qf[nb][s] = *(const bf16x8*)(qg + (size_t)(q0 + nb * 32 + l31) * 64 + s * 16 + h * 8);

  unsigned short* Kw = arena + w * 4096;
  unsigned short* Vw = Kw + 2048;
  f32x16 oacc[2][2] = {};
  float ladd[2] = {0.f, 0.f};

  // stage tile 0
  {
    const int kbase = w * 32;
#pragma unroll
    for (int i = 0; i < 4; ++i) {
      int key = i * 8 + (lane >> 3), f = lane & 7, d = f ^ (key & 7);
      gld16(kg0 + (size_t)(kbase + key) * 64 + d * 8, (void*)(Kw + (i * 64 + lane) * 8));
    }
#pragma unroll
    for (int i = 0; i < 4; ++i) {
      int dh = i * 16 + (lane >> 2), wf = lane & 3, ww = wf ^ (dh & 3);
      gld16(vg0 + (size_t)dh * 2048 + kbase + ww * 8, (void*)(Vw + (i * 64 + lane) * 8));
    }
  }

  for (int kt = 0; kt < 16; ++kt) {
    // tile kt resident only after all outstanding global->LDS DMAs retire
    __builtin_amdgcn_s_waitcnt(0x0f70);  // vmcnt(0)
    // K A-frags (m=key=l31, k=dh s*16+h*8)
    bf16x8 kf[4];
#pragma unroll
    for (int s = 0; s < 4; ++s)
      kf[s] = *(const bf16x8*)(Kw + (l31 * 8 + (((s * 2 + h) ^ (l31 & 7)))) * 8);
    // V B-frags (k=key tt*16+h*8, n=dh d2*32+l31)
    bf16x8 vf[2][2];
#pragma unroll
    for (int tt = 0; tt < 2; ++tt)
#pragma unroll
      for (int d2 = 0; d2 < 2; ++d2) {
        int dh = d2 * 32 + l31;
        vf[tt][d2] = *(const bf16x8*)(Vw + (dh * 4 + ((tt * 2 + h) ^ (dh & 3))) * 8);
      }
    // frags now requested; drain LDS reads before overwriting the tile
    __builtin_amdgcn_s_waitcnt(0xc07f);  // lgkmcnt(0)
    if (kt + 1 < 16) {
      const int kbase = (kt + 1) * 128 + w * 32;
#pragma unroll
      for (int i = 0; i < 4; ++i) {
        int key = i * 8 + (lane >> 3), f = lane & 7, d = f ^ (key & 7);
        gld16(kg0 + (size_t)(kbase + key) * 64 + d * 8, (void*)(Kw + (i * 64 + lane) * 8));
      }
#pragma unroll
      for (int i = 0; i < 4; ++i) {
        int dh = i * 16 + (lane >> 2), wf = lane & 3, ww = wf ^ (dh & 3);
        gld16(vg0 + (size_t)dh * 2048 + kbase + ww * 8, (void*)(Vw + (i * 64 + lane) * 8));
      }
    }
#pragma unroll
    for (int nb = 0; nb < 2; ++nb) {
      f32x16 sacc = {};
#pragma unroll
      for (int s = 0; s < 4; ++s)
        sacc = __builtin_amdgcn_mfma_f32_32x32x16_bf16(kf[s], qf[nb][s], sacc, 0, 0, 0);
      // exp2 (log2-domain, Q pre-scaled), pack to bf16 dwords, accumulate row-sum
      float p[16];
      float rs = 0.f;
#pragma unroll
      for (int r = 0; r < 16; ++r) {
        p[r] = __builtin_amdgcn_exp2f(sacc[r]);
        rs += p[r];
      }
      ladd[nb] += rs;
      unsigned int D[4][2];
#pragma unroll
      for (int g = 0; g < 4; ++g) {
        D[g][0] = pk2(p[4 * g + 0], p[4 * g + 1]);
        D[g][1] = pk2(p[4 * g + 2], p[4 * g + 3]);
      }
      // half-wave exchange -> PV A-frags, then PV MFMAs
#pragma unroll
      for (int tt = 0; tt < 2; ++tt) {
        unsigned int Z0 = h ? D[2 * tt][0] : D[2 * tt + 1][0];
        unsigned int Z1 = h ? D[2 * tt][1] : D[2 * tt + 1][1];
        unsigned int X0 = (unsigned int)__shfl_xor((int)Z0, 32, 64);
        unsigned int X1 = (unsigned int)__shfl_xor((int)Z1, 32, 64);
        union { unsigned int u[4]; bf16x8 v; } uu;
        uu.u[0] = h ? X0 : D[2 * tt][0];
        uu.u[1] = h ? X1 : D[2 * tt][1];
        uu.u[2] = h ? D[2 * tt + 1][0] : X0;
        uu.u[3] = h ? D[2 * tt + 1][1] : X1;
#pragma unroll
        for (int d2 = 0; d2 < 2; ++d2)
          oacc[nb][d2] = __builtin_amdgcn_mfma_f32_32x32x16_bf16(uu.v, vf[tt][d2], oacc[nb][d2], 0, 0, 0);
      }
    }
  }
  // fold key-halves of l
#pragma unroll
  for (int nb = 0; nb < 2; ++nb) ladd[nb] += __shfl_xor(ladd[nb], 32, 64);
  __syncthreads();

  const int bidx = bh >> 4, h16 = bh & 15;
  // combine: 4 rotating-chunk steps (chunk = 16 q rows)
#pragma unroll
  for (int k = 0; k < 4; ++k) {
    int c = (w + k) & 3;
    int nb = c >> 1;
#pragma unroll
    for (int d2 = 0; d2 < 2; ++d2)
#pragma unroll
      for (int r2 = 0; r2 < 8; ++r2) {
        int ql = c * 16 + (r2 & 3) + 8 * (r2 >> 2) + 4 * h;
        int addr = ql * 68 + d2 * 32 + l31;
        float v = oacc[nb][d2][(c & 1) * 8 + r2];
        if (k == 0) Obuf[addr] = v; else Obuf[addr] += v;
      }
    if (h == 0 && (l31 >> 4) == (c & 1)) {
      int qi = c * 16 + (l31 & 15);
      if (k == 0) Lbuf[qi] = ladd[nb]; else Lbuf[qi] += ladd[nb];
    }
    __syncthreads();
  }
  // normalize + coalesced store
  {
    int row = t >> 2, dh0 = (t & 3) * 16;
    float inv = 1.f / Lbuf[row];
    unsigned short o[16];
#pragma unroll
    for (int i = 0; i < 16; ++i) o[i] = f2b(Obuf[row * 68 + dh0 + i] * inv);
    size_t base = (size_t)(bidx * 2048 + q0 + row) * 1024 + h16 * 64 + dh0;
    *(uint4*)&attn[base] = *(uint4*)&o[0];
    *(uint4*)&attn[base + 8] = *(uint4*)&o[8];
  }
}

// ---------------- output projection (unchanged) ----------------
__global__ __launch_bounds__(256) void gemm_out(const unsigned short* __restrict__ Ab,
                                                const unsigned short* __restrict__ Bt,
                                                const float* __restrict__ bo,
                                                float* __restrict__ out) {
  __shared__ unsigned short As[128 * 32];
  __shared__ unsigned short Bs[128 * 32];
  const int t = threadIdx.x;
  const int lane = t & 63, wave = t >> 6;
  const int m0 = blockIdx.x * 128, n0 = blockIdx.y * 128;
  const int wr = (wave >> 1) * 64, wc = (wave & 1) * 64;
  const int fr = lane & 15, fq = lane >> 4;
  f32x4 acc[4][4] = {};
  for (int kt = 0; kt < 32; ++kt) {
    const unsigned short* Ag = Ab + (size_t)m0 * 1024 + kt * 32;
    const unsigned short* Bg = Bt + (size_t)n0 * 1024 + kt * 32;
#pragma unroll
    for (int rep = 0; rep < 2; ++rep) {
      int c = t + rep * 256;
      int row = c >> 2, col = (c & 3) * 8;
      gld16(Ag + (size_t)row * 1024 + col, (void*)(As + c * 8));
      gld16(Bg + (size_t)row * 1024 + col, (void*)(Bs + c * 8));
    }
    __syncthreads();
    bf16x8 a[4], b[4];
#pragma unroll
    for (int i = 0; i < 4; ++i) a[i] = *(const bf16x8*)&As[(wr + i * 16 + fr) * 32 + fq * 8];
#pragma unroll
    for (int j = 0; j < 4; ++j) b[j] = *(const bf16x8*)&Bs[(wc + j * 16 + fr) * 32 + fq * 8];
#pragma unroll
    for (int i = 0; i < 4; ++i)
#pragma unroll
      for (int j = 0; j < 4; ++j)
        acc[i][j] = __builtin_amdgcn_mfma_f32_16x16x32_bf16(a[i], b[j], acc[i][j], 0, 0, 0);
    __syncthreads();
  }
#pragma unroll
  for (int j = 0; j < 4; ++j) {
    int gn = n0 + wc + j * 16 + fr;
    float bias = bo[gn];
#pragma unroll
    for (int i = 0; i < 4; ++i)
#pragma unroll
      for (int r = 0; r < 4; ++r) {
        int gm = m0 + wr + i * 16 + fq * 4 + r;
        out[(size_t)gm * 1024 + gn] = acc[i][j][r] + bias;
      }
  }
}

extern "C" void kernel_launch(void* const* d_in, const int* in_sizes, int n_in,
                              void* d_out, int out_size, void* d_ws, size_t ws_size,
                              hipStream_t stream) {
  const float* x = (const float*)d_in[0];
  const float* Wq = (const float*)d_in[1];
  const float* bq = (const float*)d_in[2];
  const float* Wk = (const float*)d_in[3];
  const float* bk = (const float*)d_in[4];
  const float* Wv = (const float*)d_in[5];
  const float* bv = (const float*)d_in[6];
  const float* Wo = (const float*)d_in[7];
  const float* bo = (const float*)d_in[8];
  float* out = (float*)d_out;

  unsigned short* ws = (unsigned short*)d_ws;
  const size_t MI = (size_t)1024 * 1024;
  unsigned short* xb = ws;
  unsigned short* wt = ws + 4 * MI;
  unsigned short* qb = wt + 4 * MI;
  unsigned short* kb = qb + 4 * MI;
  unsigned short* vtb = kb + 4 * MI;
  unsigned short* attn = xb;  // reuse xb after QKV gemm

  prep_kernel<<<5120, 256, 0, stream>>>(x, Wq, Wk, Wv, Wo, xb, wt);
  gemm_qkv<<<dim3(32, 24), 256, 0, stream>>>(xb, wt, bq, bk, bv, qb, kb, vtb);
  attn_kernel<<<dim3(32, 32), 256, 0, stream>>>(qb, kb, vtb, attn);
  gemm_out<<<dim3(32, 8), 256, 0, stream>>>(attn, wt + 3 * MI, bo, out);
}

// Round 9
// 250.390 us; speedup vs baseline: 1.1667x; 1.0130x over previous
//
#include <hip/hip_runtime.h>
#include <hip/hip_bf16.h>
#include <stdint.h>

// Problem constants: B=2, S=2048, D=1024, H=16, DH=64, M = B*S = 4096.

typedef __attribute__((ext_vector_type(8))) short bf16x8;
typedef __attribute__((ext_vector_type(4))) float f32x4;
typedef __attribute__((ext_vector_type(16))) float f32x16;

__device__ __forceinline__ void gld16(const void* g, void* l) {
  __builtin_amdgcn_global_load_lds((const __attribute__((address_space(1))) void*)g,
                                   (__attribute__((address_space(3))) void*)l, 16, 0, 0);
}

__device__ __forceinline__ unsigned short f2b(float f) {
  __hip_bfloat16 h = __float2bfloat16(f);
  return *reinterpret_cast<unsigned short*>(&h);
}

__device__ __forceinline__ unsigned int pk2(float a, float b) {
  return (unsigned int)f2b(a) | ((unsigned int)f2b(b) << 16);
}

// ---------------- prep: x fp32->bf16 (blocks 0..4095) + W transpose (4096..5119) ----------------
__global__ __launch_bounds__(256) void prep_kernel(const float* __restrict__ x,
                                                   const float* __restrict__ Wq,
                                                   const float* __restrict__ Wk,
                                                   const float* __restrict__ Wv,
                                                   const float* __restrict__ Wo,
                                                   unsigned short* __restrict__ xb,
                                                   unsigned short* __restrict__ wt) {
  __shared__ unsigned short Ls[64 * 72];
  int bid = blockIdx.x;
  int t = threadIdx.x;
  if (bid < 4096) {
    int i = (bid * 256 + t) * 4;
    float4 v = *(const float4*)(x + i);
    ushort4 o = make_ushort4(f2b(v.x), f2b(v.y), f2b(v.z), f2b(v.w));
    *(ushort4*)(xb + i) = o;
    return;
  }
  int tid = bid - 4096;
  int z = tid >> 8, rem = tid & 255;
  int bx = rem & 15, by = rem >> 4;
  const float* src = (z == 0) ? Wq : (z == 1) ? Wk : (z == 2) ? Wv : Wo;
  unsigned short* dst = wt + (size_t)z * 1024 * 1024;
  int k0 = bx * 64, n0 = by * 64;
  int c4 = t & 15;
#pragma unroll
  for (int it = 0; it < 4; ++it) {
    int row = it * 16 + (t >> 4);
    float4 v = *(const float4*)(src + (k0 + row) * 1024 + n0 + c4 * 4);
    Ls[(c4 * 4 + 0) * 72 + row] = f2b(v.x);
    Ls[(c4 * 4 + 1) * 72 + row] = f2b(v.y);
    Ls[(c4 * 4 + 2) * 72 + row] = f2b(v.z);
    Ls[(c4 * 4 + 3) * 72 + row] = f2b(v.w);
  }
  __syncthreads();
  int nr = t >> 2, kc = (t & 3) * 16;
  *(uint4*)(dst + (size_t)(n0 + nr) * 1024 + k0 + kc) = *(uint4*)&Ls[nr * 72 + kc];
  *(uint4*)(dst + (size_t)(n0 + nr) * 1024 + k0 + kc + 8) = *(uint4*)&Ls[nr * 72 + kc + 8];
}

// ---------------- fused QKV GEMM (unchanged) ----------------
__global__ __launch_bounds__(256) void gemm_qkv(const unsigned short* __restrict__ Ab,
                                                const unsigned short* __restrict__ Bt,
                                                const float* __restrict__ bq,
                                                const float* __restrict__ bk,
                                                const float* __restrict__ bv,
                                                unsigned short* __restrict__ qb,
                                                unsigned short* __restrict__ kb,
                                                unsigned short* __restrict__ vtb) {
  __shared__ unsigned short As[128 * 32];
  __shared__ unsigned short Bs[128 * 32];
  __shared__ unsigned short Es[128 * 72];
  const int t = threadIdx.x;
  const int lane = t & 63, wave = t >> 6;
  const int m0 = blockIdx.x * 128, n0 = blockIdx.y * 128;
  const int wr = (wave >> 1) * 64, wc = (wave & 1) * 64;
  const int fr = lane & 15, fq = lane >> 4;
  f32x4 acc[4][4] = {};
  for (int kt = 0; kt < 32; ++kt) {
    const unsigned short* Ag = Ab + (size_t)m0 * 1024 + kt * 32;
    const unsigned short* Bg = Bt + (size_t)n0 * 1024 + kt * 32;
#pragma unroll
    for (int rep = 0; rep < 2; ++rep) {
      int c = t + rep * 256;
      int row = c >> 2, col = (c & 3) * 8;
      gld16(Ag + (size_t)row * 1024 + col, (void*)(As + c * 8));
      gld16(Bg + (size_t)row * 1024 + col, (void*)(Bs + c * 8));
    }
    __syncthreads();
    bf16x8 a[4], b[4];
#pragma unroll
    for (int i = 0; i < 4; ++i) a[i] = *(const bf16x8*)&As[(wr + i * 16 + fr) * 32 + fq * 8];
#pragma unroll
    for (int j = 0; j < 4; ++j) b[j] = *(const bf16x8*)&Bs[(wc + j * 16 + fr) * 32 + fq * 8];
#pragma unroll
    for (int i = 0; i < 4; ++i)
#pragma unroll
      for (int j = 0; j < 4; ++j)
        acc[i][j] = __builtin_amdgcn_mfma_f32_16x16x32_bf16(a[i], b[j], acc[i][j], 0, 0, 0);
    __syncthreads();
  }
  const int which = n0 >> 10;
  const int bidx = m0 >> 11, s0 = m0 & 2047;
  if (which == 2) {
#pragma unroll
    for (int nh = 0; nh < 2; ++nh) {
      if ((wc >> 6) == nh) {
#pragma unroll
        for (int j = 0; j < 4; ++j) {
          int col = j * 16 + fr;
          float bias = bv[(n0 + nh * 64 + col) & 1023];
#pragma unroll
          for (int i = 0; i < 4; ++i) {
            int sl = wr + i * 16 + fq * 4;
            ushort4 pk;
            pk.x = f2b(acc[i][j][0] + bias);
            pk.y = f2b(acc[i][j][1] + bias);
            pk.z = f2b(acc[i][j][2] + bias);
            pk.w = f2b(acc[i][j][3] + bias);
            *(uint2*)&Es[col * 136 + sl] = *(uint2*)&pk;
          }
        }
      }
      __syncthreads();
      int h = ((n0 + nh * 64) & 1023) >> 6;
#pragma unroll
      for (int it = 0; it < 4; ++it) {
        int dh = it * 16 + (t >> 4);
        int ck = (t & 15) * 8;
        uint4 vv = *(uint4*)&Es[dh * 136 + ck];
        *(uint4*)&vtb[(size_t)((bidx * 16 + h) * 64 + dh) * 2048 + s0 + ck] = vv;
      }
      __syncthreads();
    }
  } else {
    unsigned short* dst = (which == 0) ? qb : kb;
    const float* bias_p = (which == 0) ? bq : bk;
    float scale = (which == 0) ? 0.1803368801111204f : 1.0f;
#pragma unroll
    for (int nh = 0; nh < 2; ++nh) {
      if ((wc >> 6) == nh) {
#pragma unroll
        for (int j = 0; j < 4; ++j) {
          int col = j * 16 + fr;
          float bias = bias_p[(n0 + nh * 64 + col) & 1023];
#pragma unroll
          for (int i = 0; i < 4; ++i)
#pragma unroll
            for (int r = 0; r < 4; ++r) {
              int sl = wr + i * 16 + fq * 4 + r;
              Es[sl * 72 + col] = f2b((acc[i][j][r] + bias) * scale);
            }
        }
      }
      __syncthreads();
      int h = ((n0 + nh * 64) & 1023) >> 6;
#pragma unroll
      for (int it = 0; it < 4; ++it) {
        int sl = it * 32 + (t >> 3);
        int ck = (t & 7) * 8;
        uint4 vv = *(uint4*)&Es[sl * 72 + ck];
        *(uint4*)&dst[(size_t)((bidx * 16 + h) * 2048 + s0 + sl) * 64 + ck] = vv;
      }
      __syncthreads();
    }
  }
}

// ---------------- flash attention v8: v7 + (256,1) register license + fused per-tt exp/pack ----------------
// grid (32 bh, 32 q-tiles): XCD = bh%8 pins each bh's K/V to one XCD L2 (verified: FETCH 106->58 MB).
// __launch_bounds__(256,1): ~190 regs needed; 2 waves/SIMD, same occupancy as LDS cap — no spills.
__global__ __launch_bounds__(256, 1) void attn_kernel(const unsigned short* __restrict__ qb,
                                                      const unsigned short* __restrict__ kb,
                                                      const unsigned short* __restrict__ vtb,
                                                      unsigned short* __restrict__ attn) {
  __shared__ unsigned short arena[16384];  // wave w: K at w*4096 (2048 sh), V at +2048
  __shared__ float Obuf[64 * 68];
  __shared__ float Lbuf[64];
  const int t = threadIdx.x, lane = t & 63, w = t >> 6;
  const int l31 = lane & 31, h = lane >> 5;
  const int bh = blockIdx.x, q0 = blockIdx.y * 64;
  const unsigned short* qg = qb + (size_t)bh * 2048 * 64;
  const unsigned short* kg0 = kb + (size_t)bh * 2048 * 64;
  const unsigned short* vg0 = vtb + (size_t)bh * 64 * 2048;

  // Q B-fragments, register-resident: qf[nb][s] covers q = q0+nb*32+l31, dh = s*16+h*8..+7
  bf16x8 qf[2][4];
#pragma unroll
  for (int nb = 0; nb < 2; ++nb)
#pragma unroll
    for (int s = 0; s < 4; ++s)
      qf[nb][s] = *(const bf16x8*)(qg + (size_t)(q0 + nb * 32 + l31) * 64 + s * 16 + h * 8);

  unsigned short* Kw = arena + w * 4096;
  unsigned short* Vw = Kw + 2048;
  f32x16 oacc[2][2] = {};
  float ladd[2] = {0.f, 0.f};

  // stage tile 0
  {
    const int kbase = w * 32;
#pragma unroll
    for (int i = 0; i < 4; ++i) {
      int key = i * 8 + (lane >> 3), f = lane & 7, d = f ^ (key & 7);
      gld16(kg0 + (size_t)(kbase + key) * 64 + d * 8, (void*)(Kw + (i * 64 + lane) * 8));
    }
#pragma unroll
    for (int i = 0; i < 4; ++i) {
      int dh = i * 16 + (lane >> 2), wf = lane & 3, ww = wf ^ (dh & 3);
      gld16(vg0 + (size_t)dh * 2048 + kbase + ww * 8, (void*)(Vw + (i * 64 + lane) * 8));
    }
  }

  for (int kt = 0; kt < 16; ++kt) {
    // tile kt resident only after all outstanding global->LDS DMAs retire
    __builtin_amdgcn_s_waitcnt(0x0f70);  // vmcnt(0)
    // K A-frags (m=key=l31, k=dh s*16+h*8)
    bf16x8 kf[4];
#pragma unroll
    for (int s = 0; s < 4; ++s)
      kf[s] = *(const bf16x8*)(Kw + (l31 * 8 + (((s * 2 + h) ^ (l31 & 7)))) * 8);
    // V B-frags (k=key tt*16+h*8, n=dh d2*32+l31)
    bf16x8 vf[2][2];
#pragma unroll
    for (int tt = 0; tt < 2; ++tt)
#pragma unroll
      for (int d2 = 0; d2 < 2; ++d2) {
        int dh = d2 * 32 + l31;
        vf[tt][d2] = *(const bf16x8*)(Vw + (dh * 4 + ((tt * 2 + h) ^ (dh & 3))) * 8);
      }
    // frags now requested; drain LDS reads before overwriting the tile
    __builtin_amdgcn_s_waitcnt(0xc07f);  // lgkmcnt(0)
    if (kt + 1 < 16) {
      const int kbase = (kt + 1) * 128 + w * 32;
#pragma unroll
      for (int i = 0; i < 4; ++i) {
        int key = i * 8 + (lane >> 3), f = lane & 7, d = f ^ (key & 7);
        gld16(kg0 + (size_t)(kbase + key) * 64 + d * 8, (void*)(Kw + (i * 64 + lane) * 8));
      }
#pragma unroll
      for (int i = 0; i < 4; ++i) {
        int dh = i * 16 + (lane >> 2), wf = lane & 3, ww = wf ^ (dh & 3);
        gld16(vg0 + (size_t)dh * 2048 + kbase + ww * 8, (void*)(Vw + (i * 64 + lane) * 8));
      }
    }
#pragma unroll
    for (int nb = 0; nb < 2; ++nb) {
      f32x16 sacc = {};
#pragma unroll
      for (int s = 0; s < 4; ++s)
        sacc = __builtin_amdgcn_mfma_f32_32x32x16_bf16(kf[s], qf[nb][s], sacc, 0, 0, 0);
      // per-tt: exp2 (log2-domain, Q pre-scaled) -> pack -> half-wave exchange -> PV MFMA
      float rs = 0.f;
#pragma unroll
      for (int tt = 0; tt < 2; ++tt) {
        float p0, p1, p2, p3, p4, p5, p6, p7;
        p0 = __builtin_amdgcn_exp2f(sacc[8 * tt + 0]);
        p1 = __builtin_amdgcn_exp2f(sacc[8 * tt + 1]);
        p2 = __builtin_amdgcn_exp2f(sacc[8 * tt + 2]);
        p3 = __builtin_amdgcn_exp2f(sacc[8 * tt + 3]);
        p4 = __builtin_amdgcn_exp2f(sacc[8 * tt + 4]);
        p5 = __builtin_amdgcn_exp2f(sacc[8 * tt + 5]);
        p6 = __builtin_amdgcn_exp2f(sacc[8 * tt + 6]);
        p7 = __builtin_amdgcn_exp2f(sacc[8 * tt + 7]);
        rs += ((p0 + p1) + (p2 + p3)) + ((p4 + p5) + (p6 + p7));
        unsigned int Da0 = pk2(p0, p1), Da1 = pk2(p2, p3);
        unsigned int Db0 = pk2(p4, p5), Db1 = pk2(p6, p7);
        unsigned int Z0 = h ? Da0 : Db0;
        unsigned int Z1 = h ? Da1 : Db1;
        unsigned int X0 = (unsigned int)__shfl_xor((int)Z0, 32, 64);
        unsigned int X1 = (unsigned int)__shfl_xor((int)Z1, 32, 64);
        union { unsigned int u[4]; bf16x8 v; } uu;
        uu.u[0] = h ? X0 : Da0;
        uu.u[1] = h ? X1 : Da1;
        uu.u[2] = h ? Db0 : X0;
        uu.u[3] = h ? Db1 : X1;
#pragma unroll
        for (int d2 = 0; d2 < 2; ++d2)
          oacc[nb][d2] = __builtin_amdgcn_mfma_f32_32x32x16_bf16(uu.v, vf[tt][d2], oacc[nb][d2], 0, 0, 0);
      }
      ladd[nb] += rs;
    }
  }
  // fold key-halves of l
#pragma unroll
  for (int nb = 0; nb < 2; ++nb) ladd[nb] += __shfl_xor(ladd[nb], 32, 64);
  __syncthreads();

  const int bidx = bh >> 4, h16 = bh & 15;
  // combine: 4 rotating-chunk steps (chunk = 16 q rows)
#pragma unroll
  for (int k = 0; k < 4; ++k) {
    int c = (w + k) & 3;
    int nb = c >> 1;
#pragma unroll
    for (int d2 = 0; d2 < 2; ++d2)
#pragma unroll
      for (int r2 = 0; r2 < 8; ++r2) {
        int ql = c * 16 + (r2 & 3) + 8 * (r2 >> 2) + 4 * h;
        int addr = ql * 68 + d2 * 32 + l31;
        float v = oacc[nb][d2][(c & 1) * 8 + r2];
        if (k == 0) Obuf[addr] = v; else Obuf[addr] += v;
      }
    if (h == 0 && (l31 >> 4) == (c & 1)) {
      int qi = c * 16 + (l31 & 15);
      if (k == 0) Lbuf[qi] = ladd[nb]; else Lbuf[qi] += ladd[nb];
    }
    __syncthreads();
  }
  // normalize + coalesced store
  {
    int row = t >> 2, dh0 = (t & 3) * 16;
    float inv = 1.f / Lbuf[row];
    unsigned short o[16];
#pragma unroll
    for (int i = 0; i < 16; ++i) o[i] = f2b(Obuf[row * 68 + dh0 + i] * inv);
    size_t base = (size_t)(bidx * 2048 + q0 + row) * 1024 + h16 * 64 + dh0;
    *(uint4*)&attn[base] = *(uint4*)&o[0];
    *(uint4*)&attn[base + 8] = *(uint4*)&o[8];
  }
}

// ---------------- output projection (unchanged) ----------------
__global__ __launch_bounds__(256) void gemm_out(const unsigned short* __restrict__ Ab,
                                                const unsigned short* __restrict__ Bt,
                                                const float* __restrict__ bo,
                                                float* __restrict__ out) {
  __shared__ unsigned short As[128 * 32];
  __shared__ unsigned short Bs[128 * 32];
  const int t = threadIdx.x;
  const int lane = t & 63, wave = t >> 6;
  const int m0 = blockIdx.x * 128, n0 = blockIdx.y * 128;
  const int wr = (wave >> 1) * 64, wc = (wave & 1) * 64;
  const int fr = lane & 15, fq = lane >> 4;
  f32x4 acc[4][4] = {};
  for (int kt = 0; kt < 32; ++kt) {
    const unsigned short* Ag = Ab + (size_t)m0 * 1024 + kt * 32;
    const unsigned short* Bg = Bt + (size_t)n0 * 1024 + kt * 32;
#pragma unroll
    for (int rep = 0; rep < 2; ++rep) {
      int c = t + rep * 256;
      int row = c >> 2, col = (c & 3) * 8;
      gld16(Ag + (size_t)row * 1024 + col, (void*)(As + c * 8));
      gld16(Bg + (size_t)row * 1024 + col, (void*)(Bs + c * 8));
    }
    __syncthreads();
    bf16x8 a[4], b[4];
#pragma unroll
    for (int i = 0; i < 4; ++i) a[i] = *(const bf16x8*)&As[(wr + i * 16 + fr) * 32 + fq * 8];
#pragma unroll
    for (int j = 0; j < 4; ++j) b[j] = *(const bf16x8*)&Bs[(wc + j * 16 + fr) * 32 + fq * 8];
#pragma unroll
    for (int i = 0; i < 4; ++i)
#pragma unroll
      for (int j = 0; j < 4; ++j)
        acc[i][j] = __builtin_amdgcn_mfma_f32_16x16x32_bf16(a[i], b[j], acc[i][j], 0, 0, 0);
    __syncthreads();
  }
#pragma unroll
  for (int j = 0; j < 4; ++j) {
    int gn = n0 + wc + j * 16 + fr;
    float bias = bo[gn];
#pragma unroll
    for (int i = 0; i < 4; ++i)
#pragma unroll
      for (int r = 0; r < 4; ++r) {
        int gm = m0 + wr + i * 16 + fq * 4 + r;
        out[(size_t)gm * 1024 + gn] = acc[i][j][r] + bias;
      }
  }
}

extern "C" void kernel_launch(void* const* d_in, const int* in_sizes, int n_in,
                              void* d_out, int out_size, void* d_ws, size_t ws_size,
                              hipStream_t stream) {
  const float* x = (const float*)d_in[0];
  const float* Wq = (const float*)d_in[1];
  const float* bq = (const float*)d_in[2];
  const float* Wk = (const float*)d_in[3];
  const float* bk = (const float*)d_in[4];
  const float* Wv = (const float*)d_in[5];
  const float* bv = (const float*)d_in[6];
  const float* Wo = (const float*)d_in[7];
  const float* bo = (const float*)d_in[8];
  float* out = (float*)d_out;

  unsigned short* ws = (unsigned short*)d_ws;
  const size_t MI = (size_t)1024 * 1024;
  unsigned short* xb = ws;
  unsigned short* wt = ws + 4 * MI;
  unsigned short* qb = wt + 4 * MI;
  unsigned short* kb = qb + 4 * MI;
  unsigned short* vtb = kb + 4 * MI;
  unsigned short* attn = xb;  // reuse xb after QKV gemm

  prep_kernel<<<5120, 256, 0, stream>>>(x, Wq, Wk, Wv, Wo, xb, wt);
  gemm_qkv<<<dim3(32, 24), 256, 0, stream>>>(xb, wt, bq, bk, bv, qb, kb, vtb);
  attn_kernel<<<dim3(32, 32), 256, 0, stream>>>(qb, kb, vtb, attn);
  gemm_out<<<dim3(32, 8), 256, 0, stream>>>(attn, wt + 3 * MI, bo, out);
}